// Round 8
// baseline (538.711 us; speedup 1.0000x reference)
//
#include <hip/hip_runtime.h>
#include <hip/hip_bf16.h>
#include <stdint.h>

#define NB 8
#define NSEQ 1024
#define DIMM 768
#define NHEADS 12
#define DH 64
#define NQKV 2304
#define ALPHA_ 0.25f
#define SCALE_ 0.125f
#define EPS_ 1e-5f

typedef __bf16 bf16;
typedef bf16 bf16x8 __attribute__((ext_vector_type(8)));
typedef bf16 bf16x4 __attribute__((ext_vector_type(4)));
typedef float f32x4 __attribute__((ext_vector_type(4)));

#define MFMA16(a, b, c) __builtin_amdgcn_mfma_f32_16x16x32_bf16((a), (b), (c), 0, 0, 0)

static __device__ __forceinline__ void load_lds16(const void* gsrc, void* ldst) {
  __builtin_amdgcn_global_load_lds(
      (__attribute__((address_space(1))) void*)gsrc,
      (__attribute__((address_space(3))) void*)ldst, 16, 0, 0);
}

// lgkm-only barrier (no DMA staging in attn; global loads ride across)
#define BAR_LGKM()                                             \
  do {                                                         \
    __builtin_amdgcn_sched_barrier(0);                         \
    asm volatile("s_waitcnt lgkmcnt(0)" ::: "memory");         \
    __builtin_amdgcn_s_barrier();                              \
    __builtin_amdgcn_sched_barrier(0);                         \
  } while (0)

// LDS byte-offset swizzle (row stride must be ==0 mod 128B): XOR bits[6:4]
// with (row&7) ^ colbyte bits[9:7]. Preserves 16B alignment.
static __device__ __forceinline__ int swz(int row, int cb) {
  return cb ^ ((((row & 7) ^ ((cb >> 7) & 7)) << 4));
}

// ---------------- LayerNorm + bf16 cast: x(8192x768) -> xn bf16 ----------------
__global__ __launch_bounds__(256) void ln_kernel(
    const float* __restrict__ x, const float* __restrict__ gamma,
    const float* __restrict__ beta, bf16* __restrict__ xn) {
  const int row = blockIdx.x * 4 + (threadIdx.x >> 6);
  const int lane = threadIdx.x & 63;
  const float* xr = x + (size_t)row * DIMM;
  float4 v[3];
  float s = 0.f, s2 = 0.f;
#pragma unroll
  for (int c = 0; c < 3; ++c) {
    v[c] = *reinterpret_cast<const float4*>(xr + c * 256 + lane * 4);
    s += v[c].x + v[c].y + v[c].z + v[c].w;
    s2 += v[c].x * v[c].x + v[c].y * v[c].y + v[c].z * v[c].z + v[c].w * v[c].w;
  }
#pragma unroll
  for (int m = 1; m < 64; m <<= 1) {
    s += __shfl_xor(s, m);
    s2 += __shfl_xor(s2, m);
  }
  const float mu = s * (1.f / DIMM);
  const float rstd = rsqrtf(s2 * (1.f / DIMM) - mu * mu + EPS_);
#pragma unroll
  for (int c = 0; c < 3; ++c) {
    const float4 g4 = *reinterpret_cast<const float4*>(gamma + c * 256 + lane * 4);
    const float4 b4 = *reinterpret_cast<const float4*>(beta + c * 256 + lane * 4);
    bf16x4 o;
    o[0] = (bf16)((v[c].x - mu) * rstd * g4.x + b4.x);
    o[1] = (bf16)((v[c].y - mu) * rstd * g4.y + b4.y);
    o[2] = (bf16)((v[c].z - mu) * rstd * g4.z + b4.z);
    o[3] = (bf16)((v[c].w - mu) * rstd * g4.w + b4.w);
    *reinterpret_cast<bf16x4*>(xn + (size_t)row * DIMM + c * 256 + lane * 4) = o;
  }
}

// ------------- transpose + cast: f32 in[R][C] -> bf16 out[C][R] -------------
__global__ __launch_bounds__(256) void tcast_kernel(
    const float* __restrict__ in, bf16* __restrict__ out, int R, int C) {
  __shared__ float tile[32][33];
  const int tx = threadIdx.x & 31, ty = threadIdx.x >> 5;
  const int c0 = blockIdx.x * 32, r0 = blockIdx.y * 32;
#pragma unroll
  for (int i = ty; i < 32; i += 8)
    tile[i][tx] = in[(size_t)(r0 + i) * C + c0 + tx];
  __syncthreads();
#pragma unroll
  for (int i = ty; i < 32; i += 8)
    out[(size_t)(c0 + i) * R + r0 + tx] = (bf16)tile[tx][i];
}

// -------- QKV GEMM: xn(8192x768) @ wT(2304 cols x 768 k) -> q,k,vT bf16 --------
__global__ __launch_bounds__(256) void qkv_gemm(
    const bf16* __restrict__ xn, const bf16* __restrict__ wT,
    bf16* __restrict__ qb, bf16* __restrict__ kb, bf16* __restrict__ vt) {
  __shared__ __align__(16) bf16 As[128 * 32];
  __shared__ __align__(16) bf16 Bs[64 * 32];
  const int tid = threadIdx.x;
  const int wv = tid >> 6, l = tid & 63;
  const int l16 = l & 15, q4 = l >> 4;
  const int c0 = blockIdx.x * 64, row0 = blockIdx.y * 128;
  const int sr = tid >> 2, skk = (tid & 3) * 8;
  f32x4 acc0[4], acc1[4];
#pragma unroll
  for (int c = 0; c < 4; ++c) {
    acc0[c] = f32x4{0.f, 0.f, 0.f, 0.f};
    acc1[c] = f32x4{0.f, 0.f, 0.f, 0.f};
  }
  for (int k0 = 0; k0 < DIMM; k0 += 32) {
    __syncthreads();
    load_lds16(xn + (size_t)(row0 + sr) * DIMM + k0 + skk, As + tid * 8);
    load_lds16(xn + (size_t)(row0 + 64 + sr) * DIMM + k0 + skk, As + 2048 + tid * 8);
    load_lds16(wT + (size_t)(c0 + sr) * DIMM + k0 + skk, Bs + tid * 8);
    __syncthreads();
    const bf16x8 a0 = *reinterpret_cast<const bf16x8*>(&As[(wv * 32 + l16) * 32 + q4 * 8]);
    const bf16x8 a1 = *reinterpret_cast<const bf16x8*>(&As[(wv * 32 + 16 + l16) * 32 + q4 * 8]);
#pragma unroll
    for (int c = 0; c < 4; ++c) {
      const bf16x8 bb = *reinterpret_cast<const bf16x8*>(&Bs[(c * 16 + l16) * 32 + q4 * 8]);
      acc0[c] = MFMA16(a0, bb, acc0[c]);
      acc1[c] = MFMA16(a1, bb, acc1[c]);
    }
  }
  const int sect = c0 / DIMM;          // 0=q 1=k 2=v (uniform per block)
  const int head = (c0 % DIMM) >> 6;   // uniform per block
#pragma unroll
  for (int c = 0; c < 4; ++c) {
    const int dd = c * 16 + l16;
#pragma unroll
    for (int r = 0; r < 4; ++r) {
#pragma unroll
      for (int rsub = 0; rsub < 2; ++rsub) {
        const int gm = row0 + wv * 32 + rsub * 16 + q4 * 4 + r;
        const int b = gm >> 10, n = gm & 1023;
        const size_t bhh = (size_t)b * NHEADS + head;
        const float av = rsub ? acc1[c][r] : acc0[c][r];
        const bf16 val = (bf16)av;
        if (sect == 0)      qb[(bhh * NSEQ + n) * DH + dd] = val;
        else if (sect == 1) kb[(bhh * NSEQ + n) * DH + dd] = val;
        else                vt[(bhh * DH + dd) * NSEQ + n] = val;
      }
    }
  }
}

// -------- fused attention, chunked 3-phase, 8 blocks/CU --------
// Block: 16 q-rows; j processed in 2 chunks of 512 with flash-style online
// rescale. Per chunk: P1 S=QK^T (swapped) -> swizzled LDS bf16 [16][576];
// P2 wave owns 4 full rows: nontemporal h read / blended write (contiguous),
// online max/sum, P overwrites S; P3 PV with per-row rescale via scl[] LDS.
// LDS ~18.6 KB -> 8 blocks/CU; launch_bounds(256,8) caps VGPR at 64.
__global__ __launch_bounds__(256, 8) void attn_kernel(
    const bf16* __restrict__ qb, const bf16* __restrict__ kb,
    const bf16* __restrict__ vt, const float* __restrict__ h,
    float* __restrict__ blended, bf16* __restrict__ attn_out) {
  __shared__ __align__(16) char S_lds[16 * 1152];  // bf16 [16][512] + swizzle pad
  __shared__ __align__(16) float scl[16];
  __shared__ __align__(16) float lred[16];

  const int tid = threadIdx.x;
  const int wv = tid >> 6, l = tid & 63;
  const int l16 = l & 15, q4 = l >> 4;
  const int i0 = blockIdx.x * 16;
  const int bh = blockIdx.y;

  const float* hbase = h + ((size_t)bh << 20);
  float* bbase = blended + ((size_t)bh << 20);
  const bf16* kbase = kb + (size_t)bh * NSEQ * DH;
  const bf16* vbase = vt + (size_t)bh * DH * NSEQ;

  bf16x8 qT[2];
#pragma unroll
  for (int w2 = 0; w2 < 2; ++w2)
    qT[w2] = *reinterpret_cast<const bf16x8*>(
        qb + ((size_t)bh * NSEQ + i0 + l16) * DH + w2 * 32 + q4 * 8);

  f32x4 acc[4];
#pragma unroll
  for (int kk = 0; kk < 4; ++kk) acc[kk] = f32x4{0.f, 0.f, 0.f, 0.f};
  float m_run[4], l_run[4];
#pragma unroll
  for (int r = 0; r < 4; ++r) { m_run[r] = -1e30f; l_run[r] = 0.f; }

#pragma unroll
  for (int c = 0; c < 2; ++c) {
    // ---- P1: S chunk -> LDS (wave strip = 128 cols x all 16 rows) ----
    {
      const bf16* kq = kbase + (size_t)(c * 512 + wv * 128 + l16) * DH + q4 * 8;
      char* srow_w = S_lds + l16 * 1152;
#pragma unroll
      for (int st = 0; st < 2; ++st) {
        f32x4 s[4];
#pragma unroll
        for (int js = 0; js < 4; ++js) s[js] = f32x4{0.f, 0.f, 0.f, 0.f};
#pragma unroll
        for (int js = 0; js < 4; ++js) {
#pragma unroll
          for (int w2 = 0; w2 < 2; ++w2) {
            const bf16x8 kf = *reinterpret_cast<const bf16x8*>(
                kq + (size_t)(st * 64 + js * 16) * DH + w2 * 32);
            s[js] = MFMA16(kf, qT[w2], s[js]);
          }
        }
#pragma unroll
        for (int js = 0; js < 4; ++js) {
          bf16x4 pk;
#pragma unroll
          for (int r = 0; r < 4; ++r) pk[r] = (bf16)(s[js][r] * (ALPHA_ * SCALE_));
          const int cb = (wv * 256 + st * 128 + js * 32 + q4 * 8);
          *reinterpret_cast<bf16x4*>(srow_w + swz(l16, cb)) = pk;
        }
      }
    }
    BAR_LGKM();  // S visible

    // ---- P2: stream 4 full rows (512 cols each); online softmax; P->LDS ----
#pragma unroll
    for (int rr = 0; rr < 4; ++rr) {
      const int row = wv * 4 + rr;
      char* srow = S_lds + row * 1152;
      const bf16x8 sv = *reinterpret_cast<const bf16x8*>(srow + swz(row, l * 16));
      const float* hp = hbase + (size_t)(i0 + row) * NSEQ + c * 512 + l * 8;
      const f32x4 h0 = __builtin_nontemporal_load(reinterpret_cast<const f32x4*>(hp));
      const f32x4 h1 = __builtin_nontemporal_load(reinterpret_cast<const f32x4*>(hp + 4));
      float bl[8];
#pragma unroll
      for (int t = 0; t < 4; ++t) bl[t] = fmaf(0.75f, h0[t], (float)sv[t]);
#pragma unroll
      for (int t = 0; t < 4; ++t) bl[4 + t] = fmaf(0.75f, h1[t], (float)sv[4 + t]);
      float* bp = bbase + (size_t)(i0 + row) * NSEQ + c * 512 + l * 8;
      f32x4 b0, b1;
#pragma unroll
      for (int t = 0; t < 4; ++t) { b0[t] = bl[t]; b1[t] = bl[4 + t]; }
      __builtin_nontemporal_store(b0, reinterpret_cast<f32x4*>(bp));
      __builtin_nontemporal_store(b1, reinterpret_cast<f32x4*>(bp + 4));
      float tm = bl[0];
#pragma unroll
      for (int t = 1; t < 8; ++t) tm = fmaxf(tm, bl[t]);
#pragma unroll
      for (int mm = 1; mm < 64; mm <<= 1) tm = fmaxf(tm, __shfl_xor(tm, mm));
      const float mnew = fmaxf(m_run[rr], tm);
      const float sc = __expf(m_run[rr] - mnew);
      m_run[rr] = mnew;
      float rs = 0.f;
      bf16x8 pk;
#pragma unroll
      for (int t = 0; t < 8; ++t) {
        const float p = __expf(bl[t] - mnew);
        rs += p;
        pk[t] = (bf16)p;
      }
      *reinterpret_cast<bf16x8*>(srow + swz(row, l * 16)) = pk;
#pragma unroll
      for (int mm = 1; mm < 64; mm <<= 1) rs += __shfl_xor(rs, mm);
      l_run[rr] = l_run[rr] * sc + rs;
      if (l == 0) {
        scl[row] = sc;
        if (c == 1) lred[row] = l_run[rr];
      }
    }
    BAR_LGKM();  // P, scl (and final lred) visible

    // ---- P3: acc = acc*scl + P @ V^T (wave owns d-strip wv*16..+15) ----
    {
      const f32x4 sclv = *reinterpret_cast<const f32x4*>(&scl[q4 * 4]);
      const bf16* vq = vbase + (size_t)(wv * 16 + l16) * NSEQ + c * 512 + q4 * 8;
      char* prow = S_lds + l16 * 1152;
#pragma unroll
      for (int kk = 0; kk < 4; ++kk) acc[kk] *= sclv;
#pragma unroll
      for (int kk = 0; kk < 4; ++kk) {
#pragma unroll
        for (int ki = 0; ki < 4; ++ki) {
          const int ks = kk * 4 + ki;
          const bf16x8 pa = *reinterpret_cast<const bf16x8*>(
              prow + swz(l16, ks * 64 + q4 * 16));
          const bf16x8 vf = *reinterpret_cast<const bf16x8*>(vq + ks * 32);
          acc[kk] = MFMA16(pa, vf, acc[kk]);
        }
      }
    }
    if (c == 0) BAR_LGKM();  // S_lds free for next chunk's P1
  }

  // ---- epilogue: normalize, write attn_out (no cross-wave O merge) ----
  const f32x4 lv = *reinterpret_cast<const f32x4*>(&lred[q4 * 4]);
  const f32x4 af = (acc[0] + acc[1]) + (acc[2] + acc[3]);
  const int b = bh / NHEADS, head = bh % NHEADS;
#pragma unroll
  for (int r = 0; r < 4; ++r) {
    const int q = q4 * 4 + r;
    attn_out[((size_t)b * NSEQ + i0 + q) * DIMM + head * DH + wv * 16 + l16] =
        (bf16)(af[r] / lv[r]);
  }
}

// -------- output projection: attn_out(8192x768) @ woutT + b_out -> f32 out --------
__global__ __launch_bounds__(256) void oproj_gemm(
    const bf16* __restrict__ ain, const bf16* __restrict__ wT,
    const float* __restrict__ bias, float* __restrict__ out) {
  __shared__ __align__(16) bf16 As[128 * 32];
  __shared__ __align__(16) bf16 Bs[64 * 32];
  const int tid = threadIdx.x;
  const int wv = tid >> 6, l = tid & 63;
  const int l16 = l & 15, q4 = l >> 4;
  const int c0 = blockIdx.x * 64, row0 = blockIdx.y * 128;
  const int sr = tid >> 2, skk = (tid & 3) * 8;
  f32x4 acc0[4], acc1[4];
#pragma unroll
  for (int c = 0; c < 4; ++c) {
    acc0[c] = f32x4{0.f, 0.f, 0.f, 0.f};
    acc1[c] = f32x4{0.f, 0.f, 0.f, 0.f};
  }
  for (int k0 = 0; k0 < DIMM; k0 += 32) {
    __syncthreads();
    load_lds16(ain + (size_t)(row0 + sr) * DIMM + k0 + skk, As + tid * 8);
    load_lds16(ain + (size_t)(row0 + 64 + sr) * DIMM + k0 + skk, As + 2048 + tid * 8);
    load_lds16(wT + (size_t)(c0 + sr) * DIMM + k0 + skk, Bs + tid * 8);
    __syncthreads();
    const bf16x8 a0 = *reinterpret_cast<const bf16x8*>(&As[(wv * 32 + l16) * 32 + q4 * 8]);
    const bf16x8 a1 = *reinterpret_cast<const bf16x8*>(&As[(wv * 32 + 16 + l16) * 32 + q4 * 8]);
#pragma unroll
    for (int c = 0; c < 4; ++c) {
      const bf16x8 bb = *reinterpret_cast<const bf16x8*>(&Bs[(c * 16 + l16) * 32 + q4 * 8]);
      acc0[c] = MFMA16(a0, bb, acc0[c]);
      acc1[c] = MFMA16(a1, bb, acc1[c]);
    }
  }
#pragma unroll
  for (int c = 0; c < 4; ++c) {
    const int gc = c0 + c * 16 + l16;
    const float bv = bias[gc];
#pragma unroll
    for (int r = 0; r < 4; ++r) {
      out[(size_t)(row0 + wv * 32 + q4 * 4 + r) * DIMM + gc] = acc0[c][r] + bv;
      out[(size_t)(row0 + wv * 32 + 16 + q4 * 4 + r) * DIMM + gc] = acc1[c][r] + bv;
    }
  }
}

extern "C" void kernel_launch(void* const* d_in, const int* in_sizes, int n_in,
                              void* d_out, int out_size, void* d_ws, size_t ws_size,
                              hipStream_t stream) {
  const float* x = (const float*)d_in[0];
  const float* h = (const float*)d_in[1];
  const float* gamma = (const float*)d_in[2];
  const float* beta = (const float*)d_in[3];
  const float* w_qkv = (const float*)d_in[4];
  const float* w_out = (const float*)d_in[5];
  const float* b_out = (const float*)d_in[6];
  float* out = (float*)d_out;
  float* blended = out + (size_t)NB * NSEQ * DIMM;

  char* ws = (char*)d_ws;
  bf16* xn = (bf16*)(ws);                   // 12.6 MB; reused as attn_out after qkv_gemm
  bf16* qb = (bf16*)(ws + 12582912);
  bf16* kb = (bf16*)(ws + 25165824);
  bf16* vt = (bf16*)(ws + 37748736);
  bf16* wqkvT = (bf16*)(ws + 50331648);
  bf16* woutT = (bf16*)(ws + 53870592);

  hipLaunchKernelGGL(ln_kernel, dim3(2048), dim3(256), 0, stream, x, gamma, beta, xn);
  hipLaunchKernelGGL(tcast_kernel, dim3(72, 24), dim3(256), 0, stream, w_qkv, wqkvT, DIMM, NQKV);
  hipLaunchKernelGGL(tcast_kernel, dim3(24, 24), dim3(256), 0, stream, w_out, woutT, DIMM, DIMM);
  hipLaunchKernelGGL(qkv_gemm, dim3(36, 64), dim3(256), 0, stream, xn, wqkvT, qb, kb, vt);
  hipLaunchKernelGGL(attn_kernel, dim3(64, 96), dim3(256), 0, stream, qb, kb, vt, h, blended, xn);
  hipLaunchKernelGGL(oproj_gemm, dim3(12, 64), dim3(256), 0, stream, xn, woutT, b_out, out);
}

// Round 9
// 430.042 us; speedup vs baseline: 1.2527x; 1.2527x over previous
//
#include <hip/hip_runtime.h>
#include <hip/hip_bf16.h>
#include <stdint.h>

#define NB 8
#define NSEQ 1024
#define DIMM 768
#define NHEADS 12
#define DH 64
#define NQKV 2304
#define ALPHA_ 0.25f
#define SCALE_ 0.125f
#define EPS_ 1e-5f

typedef __bf16 bf16;
typedef bf16 bf16x8 __attribute__((ext_vector_type(8)));
typedef bf16 bf16x4 __attribute__((ext_vector_type(4)));
typedef float f32x4 __attribute__((ext_vector_type(4)));

#define MFMA16(a, b, c) __builtin_amdgcn_mfma_f32_16x16x32_bf16((a), (b), (c), 0, 0, 0)

static __device__ __forceinline__ void load_lds16(const void* gsrc, void* ldst) {
  __builtin_amdgcn_global_load_lds(
      (__attribute__((address_space(1))) void*)gsrc,
      (__attribute__((address_space(3))) void*)ldst, 16, 0, 0);
}

// lgkm-only barrier (no DMA staging in attn; global loads ride across)
#define BAR_LGKM()                                             \
  do {                                                         \
    __builtin_amdgcn_sched_barrier(0);                         \
    asm volatile("s_waitcnt lgkmcnt(0)" ::: "memory");         \
    __builtin_amdgcn_s_barrier();                              \
    __builtin_amdgcn_sched_barrier(0);                         \
  } while (0)

// LDS byte-offset swizzle (row stride must be ==0 mod 128B): XOR bits[6:4]
// with (row&7) ^ colbyte bits[9:7]. Preserves 16B alignment.
static __device__ __forceinline__ int swz(int row, int cb) {
  return cb ^ ((((row & 7) ^ ((cb >> 7) & 7)) << 4));
}

// ---------------- LayerNorm + bf16 cast: x(8192x768) -> xn bf16 ----------------
__global__ __launch_bounds__(256) void ln_kernel(
    const float* __restrict__ x, const float* __restrict__ gamma,
    const float* __restrict__ beta, bf16* __restrict__ xn) {
  const int row = blockIdx.x * 4 + (threadIdx.x >> 6);
  const int lane = threadIdx.x & 63;
  const float* xr = x + (size_t)row * DIMM;
  float4 v[3];
  float s = 0.f, s2 = 0.f;
#pragma unroll
  for (int c = 0; c < 3; ++c) {
    v[c] = *reinterpret_cast<const float4*>(xr + c * 256 + lane * 4);
    s += v[c].x + v[c].y + v[c].z + v[c].w;
    s2 += v[c].x * v[c].x + v[c].y * v[c].y + v[c].z * v[c].z + v[c].w * v[c].w;
  }
#pragma unroll
  for (int m = 1; m < 64; m <<= 1) {
    s += __shfl_xor(s, m);
    s2 += __shfl_xor(s2, m);
  }
  const float mu = s * (1.f / DIMM);
  const float rstd = rsqrtf(s2 * (1.f / DIMM) - mu * mu + EPS_);
#pragma unroll
  for (int c = 0; c < 3; ++c) {
    const float4 g4 = *reinterpret_cast<const float4*>(gamma + c * 256 + lane * 4);
    const float4 b4 = *reinterpret_cast<const float4*>(beta + c * 256 + lane * 4);
    bf16x4 o;
    o[0] = (bf16)((v[c].x - mu) * rstd * g4.x + b4.x);
    o[1] = (bf16)((v[c].y - mu) * rstd * g4.y + b4.y);
    o[2] = (bf16)((v[c].z - mu) * rstd * g4.z + b4.z);
    o[3] = (bf16)((v[c].w - mu) * rstd * g4.w + b4.w);
    *reinterpret_cast<bf16x4*>(xn + (size_t)row * DIMM + c * 256 + lane * 4) = o;
  }
}

// ------------- transpose + cast: f32 in[R][C] -> bf16 out[C][R] -------------
__global__ __launch_bounds__(256) void tcast_kernel(
    const float* __restrict__ in, bf16* __restrict__ out, int R, int C) {
  __shared__ float tile[32][33];
  const int tx = threadIdx.x & 31, ty = threadIdx.x >> 5;
  const int c0 = blockIdx.x * 32, r0 = blockIdx.y * 32;
#pragma unroll
  for (int i = ty; i < 32; i += 8)
    tile[i][tx] = in[(size_t)(r0 + i) * C + c0 + tx];
  __syncthreads();
#pragma unroll
  for (int i = ty; i < 32; i += 8)
    out[(size_t)(c0 + i) * R + r0 + tx] = (bf16)tile[tx][i];
}

// -------- QKV GEMM: xn(8192x768) @ wT(2304 cols x 768 k) -> q,k,vT bf16 --------
__global__ __launch_bounds__(256) void qkv_gemm(
    const bf16* __restrict__ xn, const bf16* __restrict__ wT,
    bf16* __restrict__ qb, bf16* __restrict__ kb, bf16* __restrict__ vt) {
  __shared__ __align__(16) bf16 As[128 * 32];
  __shared__ __align__(16) bf16 Bs[64 * 32];
  const int tid = threadIdx.x;
  const int wv = tid >> 6, l = tid & 63;
  const int l16 = l & 15, q4 = l >> 4;
  const int c0 = blockIdx.x * 64, row0 = blockIdx.y * 128;
  const int sr = tid >> 2, skk = (tid & 3) * 8;
  f32x4 acc0[4], acc1[4];
#pragma unroll
  for (int c = 0; c < 4; ++c) {
    acc0[c] = f32x4{0.f, 0.f, 0.f, 0.f};
    acc1[c] = f32x4{0.f, 0.f, 0.f, 0.f};
  }
  for (int k0 = 0; k0 < DIMM; k0 += 32) {
    __syncthreads();
    load_lds16(xn + (size_t)(row0 + sr) * DIMM + k0 + skk, As + tid * 8);
    load_lds16(xn + (size_t)(row0 + 64 + sr) * DIMM + k0 + skk, As + 2048 + tid * 8);
    load_lds16(wT + (size_t)(c0 + sr) * DIMM + k0 + skk, Bs + tid * 8);
    __syncthreads();
    const bf16x8 a0 = *reinterpret_cast<const bf16x8*>(&As[(wv * 32 + l16) * 32 + q4 * 8]);
    const bf16x8 a1 = *reinterpret_cast<const bf16x8*>(&As[(wv * 32 + 16 + l16) * 32 + q4 * 8]);
#pragma unroll
    for (int c = 0; c < 4; ++c) {
      const bf16x8 bb = *reinterpret_cast<const bf16x8*>(&Bs[(c * 16 + l16) * 32 + q4 * 8]);
      acc0[c] = MFMA16(a0, bb, acc0[c]);
      acc1[c] = MFMA16(a1, bb, acc1[c]);
    }
  }
  const int sect = c0 / DIMM;          // 0=q 1=k 2=v (uniform per block)
  const int head = (c0 % DIMM) >> 6;   // uniform per block
#pragma unroll
  for (int c = 0; c < 4; ++c) {
    const int dd = c * 16 + l16;
#pragma unroll
    for (int r = 0; r < 4; ++r) {
#pragma unroll
      for (int rsub = 0; rsub < 2; ++rsub) {
        const int gm = row0 + wv * 32 + rsub * 16 + q4 * 4 + r;
        const int b = gm >> 10, n = gm & 1023;
        const size_t bhh = (size_t)b * NHEADS + head;
        const float av = rsub ? acc1[c][r] : acc0[c][r];
        const bf16 val = (bf16)av;
        if (sect == 0)      qb[(bhh * NSEQ + n) * DH + dd] = val;
        else if (sect == 1) kb[(bhh * NSEQ + n) * DH + dd] = val;
        else                vt[(bhh * DH + dd) * NSEQ + n] = val;
      }
    }
  }
}

// -------- fused attention, chunked 3-phase (R8 structure, sane VGPR cap) ------
// Block: 16 q-rows; j processed in 2 chunks of 512 with flash-style online
// rescale. Per chunk: P1 S=QK^T (swapped) -> swizzled LDS bf16; P2 wave owns
// 4 full rows: nontemporal h read / blended write (contiguous 2KB/row bursts),
// online max/sum, P overwrites S; P3 PV with per-row rescale via scl[] LDS.
// LDS ~18.9 KB -> 8 blocks/CU by LDS; launch_bounds(256,4) lets VGPR float
// to ~64-80 (no spill) -> 6-8 blocks/CU.
__global__ __launch_bounds__(256, 4) void attn_kernel(
    const bf16* __restrict__ qb, const bf16* __restrict__ kb,
    const bf16* __restrict__ vt, const float* __restrict__ h,
    float* __restrict__ blended, bf16* __restrict__ attn_out) {
  __shared__ __align__(16) char S_lds[16 * 1152];  // bf16 [16][512] + swizzle pad
  __shared__ __align__(16) float scl[16];
  __shared__ __align__(16) float lred[16];

  const int tid = threadIdx.x;
  const int wv = tid >> 6, l = tid & 63;
  const int l16 = l & 15, q4 = l >> 4;
  const int i0 = blockIdx.x * 16;
  const int bh = blockIdx.y;

  const float* hbase = h + ((size_t)bh << 20);
  float* bbase = blended + ((size_t)bh << 20);
  const bf16* kbase = kb + (size_t)bh * NSEQ * DH;
  const bf16* vbase = vt + (size_t)bh * DH * NSEQ;

  bf16x8 qT[2];
#pragma unroll
  for (int w2 = 0; w2 < 2; ++w2)
    qT[w2] = *reinterpret_cast<const bf16x8*>(
        qb + ((size_t)bh * NSEQ + i0 + l16) * DH + w2 * 32 + q4 * 8);

  f32x4 acc[4];
#pragma unroll
  for (int kk = 0; kk < 4; ++kk) acc[kk] = f32x4{0.f, 0.f, 0.f, 0.f};
  float m_run[4], l_run[4];
#pragma unroll
  for (int r = 0; r < 4; ++r) { m_run[r] = -1e30f; l_run[r] = 0.f; }

#pragma unroll
  for (int c = 0; c < 2; ++c) {
    // ---- P1: S chunk -> LDS (wave strip = 128 cols x all 16 rows) ----
    {
      const bf16* kq = kbase + (size_t)(c * 512 + wv * 128 + l16) * DH + q4 * 8;
      char* srow_w = S_lds + l16 * 1152;
#pragma unroll
      for (int st = 0; st < 2; ++st) {
        f32x4 s[4];
#pragma unroll
        for (int js = 0; js < 4; ++js) s[js] = f32x4{0.f, 0.f, 0.f, 0.f};
#pragma unroll
        for (int js = 0; js < 4; ++js) {
#pragma unroll
          for (int w2 = 0; w2 < 2; ++w2) {
            const bf16x8 kf = *reinterpret_cast<const bf16x8*>(
                kq + (size_t)(st * 64 + js * 16) * DH + w2 * 32);
            s[js] = MFMA16(kf, qT[w2], s[js]);
          }
        }
#pragma unroll
        for (int js = 0; js < 4; ++js) {
          bf16x4 pk;
#pragma unroll
          for (int r = 0; r < 4; ++r) pk[r] = (bf16)(s[js][r] * (ALPHA_ * SCALE_));
          const int cb = (wv * 256 + st * 128 + js * 32 + q4 * 8);
          *reinterpret_cast<bf16x4*>(srow_w + swz(l16, cb)) = pk;
        }
      }
    }
    BAR_LGKM();  // S visible

    // ---- P2: stream 4 full rows (512 cols each); online softmax; P->LDS ----
#pragma unroll
    for (int rr = 0; rr < 4; ++rr) {
      const int row = wv * 4 + rr;
      char* srow = S_lds + row * 1152;
      const bf16x8 sv = *reinterpret_cast<const bf16x8*>(srow + swz(row, l * 16));
      const float* hp = hbase + (size_t)(i0 + row) * NSEQ + c * 512 + l * 8;
      const f32x4 h0 = __builtin_nontemporal_load(reinterpret_cast<const f32x4*>(hp));
      const f32x4 h1 = __builtin_nontemporal_load(reinterpret_cast<const f32x4*>(hp + 4));
      float bl[8];
#pragma unroll
      for (int t = 0; t < 4; ++t) bl[t] = fmaf(0.75f, h0[t], (float)sv[t]);
#pragma unroll
      for (int t = 0; t < 4; ++t) bl[4 + t] = fmaf(0.75f, h1[t], (float)sv[4 + t]);
      float* bp = bbase + (size_t)(i0 + row) * NSEQ + c * 512 + l * 8;
      f32x4 b0, b1;
#pragma unroll
      for (int t = 0; t < 4; ++t) { b0[t] = bl[t]; b1[t] = bl[4 + t]; }
      __builtin_nontemporal_store(b0, reinterpret_cast<f32x4*>(bp));
      __builtin_nontemporal_store(b1, reinterpret_cast<f32x4*>(bp + 4));
      float tm = bl[0];
#pragma unroll
      for (int t = 1; t < 8; ++t) tm = fmaxf(tm, bl[t]);
#pragma unroll
      for (int mm = 1; mm < 64; mm <<= 1) tm = fmaxf(tm, __shfl_xor(tm, mm));
      const float mnew = fmaxf(m_run[rr], tm);
      const float sc = __expf(m_run[rr] - mnew);
      m_run[rr] = mnew;
      float rs = 0.f;
      bf16x8 pk;
#pragma unroll
      for (int t = 0; t < 8; ++t) {
        const float p = __expf(bl[t] - mnew);
        rs += p;
        pk[t] = (bf16)p;
      }
      *reinterpret_cast<bf16x8*>(srow + swz(row, l * 16)) = pk;
#pragma unroll
      for (int mm = 1; mm < 64; mm <<= 1) rs += __shfl_xor(rs, mm);
      l_run[rr] = l_run[rr] * sc + rs;
      if (l == 0) {
        scl[row] = sc;
        if (c == 1) lred[row] = l_run[rr];
      }
    }
    BAR_LGKM();  // P, scl (and final lred) visible

    // ---- P3: acc = acc*scl + P @ V^T (wave owns d-strip wv*16..+15) ----
    {
      const f32x4 sclv = *reinterpret_cast<const f32x4*>(&scl[q4 * 4]);
      const bf16* vq = vbase + (size_t)(wv * 16 + l16) * NSEQ + c * 512 + q4 * 8;
      char* prow = S_lds + l16 * 1152;
#pragma unroll
      for (int kk = 0; kk < 4; ++kk) acc[kk] *= sclv;
#pragma unroll
      for (int kk = 0; kk < 4; ++kk) {
#pragma unroll
        for (int ki = 0; ki < 4; ++ki) {
          const int ks = kk * 4 + ki;
          const bf16x8 pa = *reinterpret_cast<const bf16x8*>(
              prow + swz(l16, ks * 64 + q4 * 16));
          const bf16x8 vf = *reinterpret_cast<const bf16x8*>(vq + ks * 32);
          acc[kk] = MFMA16(pa, vf, acc[kk]);
        }
      }
    }
    if (c == 0) BAR_LGKM();  // S_lds free for next chunk's P1
  }

  // ---- epilogue: normalize, write attn_out (no cross-wave O merge) ----
  const f32x4 lv = *reinterpret_cast<const f32x4*>(&lred[q4 * 4]);
  const f32x4 af = (acc[0] + acc[1]) + (acc[2] + acc[3]);
  const int b = bh / NHEADS, head = bh % NHEADS;
#pragma unroll
  for (int r = 0; r < 4; ++r) {
    const int q = q4 * 4 + r;
    attn_out[((size_t)b * NSEQ + i0 + q) * DIMM + head * DH + wv * 16 + l16] =
        (bf16)(af[r] / lv[r]);
  }
}

// -------- output projection: attn_out(8192x768) @ woutT + b_out -> f32 out --------
__global__ __launch_bounds__(256) void oproj_gemm(
    const bf16* __restrict__ ain, const bf16* __restrict__ wT,
    const float* __restrict__ bias, float* __restrict__ out) {
  __shared__ __align__(16) bf16 As[128 * 32];
  __shared__ __align__(16) bf16 Bs[64 * 32];
  const int tid = threadIdx.x;
  const int wv = tid >> 6, l = tid & 63;
  const int l16 = l & 15, q4 = l >> 4;
  const int c0 = blockIdx.x * 64, row0 = blockIdx.y * 128;
  const int sr = tid >> 2, skk = (tid & 3) * 8;
  f32x4 acc0[4], acc1[4];
#pragma unroll
  for (int c = 0; c < 4; ++c) {
    acc0[c] = f32x4{0.f, 0.f, 0.f, 0.f};
    acc1[c] = f32x4{0.f, 0.f, 0.f, 0.f};
  }
  for (int k0 = 0; k0 < DIMM; k0 += 32) {
    __syncthreads();
    load_lds16(ain + (size_t)(row0 + sr) * DIMM + k0 + skk, As + tid * 8);
    load_lds16(ain + (size_t)(row0 + 64 + sr) * DIMM + k0 + skk, As + 2048 + tid * 8);
    load_lds16(wT + (size_t)(c0 + sr) * DIMM + k0 + skk, Bs + tid * 8);
    __syncthreads();
    const bf16x8 a0 = *reinterpret_cast<const bf16x8*>(&As[(wv * 32 + l16) * 32 + q4 * 8]);
    const bf16x8 a1 = *reinterpret_cast<const bf16x8*>(&As[(wv * 32 + 16 + l16) * 32 + q4 * 8]);
#pragma unroll
    for (int c = 0; c < 4; ++c) {
      const bf16x8 bb = *reinterpret_cast<const bf16x8*>(&Bs[(c * 16 + l16) * 32 + q4 * 8]);
      acc0[c] = MFMA16(a0, bb, acc0[c]);
      acc1[c] = MFMA16(a1, bb, acc1[c]);
    }
  }
#pragma unroll
  for (int c = 0; c < 4; ++c) {
    const int gc = c0 + c * 16 + l16;
    const float bv = bias[gc];
#pragma unroll
    for (int r = 0; r < 4; ++r) {
      out[(size_t)(row0 + wv * 32 + q4 * 4 + r) * DIMM + gc] = acc0[c][r] + bv;
      out[(size_t)(row0 + wv * 32 + 16 + q4 * 4 + r) * DIMM + gc] = acc1[c][r] + bv;
    }
  }
}

extern "C" void kernel_launch(void* const* d_in, const int* in_sizes, int n_in,
                              void* d_out, int out_size, void* d_ws, size_t ws_size,
                              hipStream_t stream) {
  const float* x = (const float*)d_in[0];
  const float* h = (const float*)d_in[1];
  const float* gamma = (const float*)d_in[2];
  const float* beta = (const float*)d_in[3];
  const float* w_qkv = (const float*)d_in[4];
  const float* w_out = (const float*)d_in[5];
  const float* b_out = (const float*)d_in[6];
  float* out = (float*)d_out;
  float* blended = out + (size_t)NB * NSEQ * DIMM;

  char* ws = (char*)d_ws;
  bf16* xn = (bf16*)(ws);                   // 12.6 MB; reused as attn_out after qkv_gemm
  bf16* qb = (bf16*)(ws + 12582912);
  bf16* kb = (bf16*)(ws + 25165824);
  bf16* vt = (bf16*)(ws + 37748736);
  bf16* wqkvT = (bf16*)(ws + 50331648);
  bf16* woutT = (bf16*)(ws + 53870592);

  hipLaunchKernelGGL(ln_kernel, dim3(2048), dim3(256), 0, stream, x, gamma, beta, xn);
  hipLaunchKernelGGL(tcast_kernel, dim3(72, 24), dim3(256), 0, stream, w_qkv, wqkvT, DIMM, NQKV);
  hipLaunchKernelGGL(tcast_kernel, dim3(24, 24), dim3(256), 0, stream, w_out, woutT, DIMM, DIMM);
  hipLaunchKernelGGL(qkv_gemm, dim3(36, 64), dim3(256), 0, stream, xn, wqkvT, qb, kb, vt);
  hipLaunchKernelGGL(attn_kernel, dim3(64, 96), dim3(256), 0, stream, qb, kb, vt, h, blended, xn);
  hipLaunchKernelGGL(oproj_gemm, dim3(12, 64), dim3(256), 0, stream, xn, woutT, b_out, out);
}

// Round 10
// 403.203 us; speedup vs baseline: 1.3361x; 1.0666x over previous
//
#include <hip/hip_runtime.h>
#include <hip/hip_bf16.h>
#include <stdint.h>

#define NB 8
#define NSEQ 1024
#define DIMM 768
#define NHEADS 12
#define DH 64
#define NQKV 2304
#define ALPHA_ 0.25f
#define SCALE_ 0.125f
#define EPS_ 1e-5f

typedef __bf16 bf16;
typedef bf16 bf16x8 __attribute__((ext_vector_type(8)));
typedef bf16 bf16x4 __attribute__((ext_vector_type(4)));
typedef float f32x4 __attribute__((ext_vector_type(4)));

#define MFMA16(a, b, c) __builtin_amdgcn_mfma_f32_16x16x32_bf16((a), (b), (c), 0, 0, 0)

static __device__ __forceinline__ void load_lds16(const void* gsrc, void* ldst) {
  __builtin_amdgcn_global_load_lds(
      (__attribute__((address_space(1))) void*)gsrc,
      (__attribute__((address_space(3))) void*)ldst, 16, 0, 0);
}

// lgkm-only barrier (in-flight global loads / DMAs ride across)
#define BAR_LGKM()                                             \
  do {                                                         \
    __builtin_amdgcn_sched_barrier(0);                         \
    asm volatile("s_waitcnt lgkmcnt(0)" ::: "memory");         \
    __builtin_amdgcn_s_barrier();                              \
    __builtin_amdgcn_sched_barrier(0);                         \
  } while (0)

// wave-local drain of this wave's DMAs (no barrier)
#define WAIT_VM0()                                            \
  do {                                                        \
    __builtin_amdgcn_sched_barrier(0);                        \
    asm volatile("s_waitcnt vmcnt(0)" ::: "memory");          \
    __builtin_amdgcn_sched_barrier(0);                        \
  } while (0)

// LDS byte-offset swizzle (row stride ==0 mod 128B): XOR bits[6:4] with
// (row&7) ^ colbyte bits[9:7]. Preserves 16B alignment.
static __device__ __forceinline__ int swz(int row, int cb) {
  return cb ^ ((((row & 7) ^ ((cb >> 7) & 7)) << 4));
}

// ---------------- LayerNorm + bf16 cast: x(8192x768) -> xn bf16 ----------------
__global__ __launch_bounds__(256) void ln_kernel(
    const float* __restrict__ x, const float* __restrict__ gamma,
    const float* __restrict__ beta, bf16* __restrict__ xn) {
  const int row = blockIdx.x * 4 + (threadIdx.x >> 6);
  const int lane = threadIdx.x & 63;
  const float* xr = x + (size_t)row * DIMM;
  float4 v[3];
  float s = 0.f, s2 = 0.f;
#pragma unroll
  for (int c = 0; c < 3; ++c) {
    v[c] = *reinterpret_cast<const float4*>(xr + c * 256 + lane * 4);
    s += v[c].x + v[c].y + v[c].z + v[c].w;
    s2 += v[c].x * v[c].x + v[c].y * v[c].y + v[c].z * v[c].z + v[c].w * v[c].w;
  }
#pragma unroll
  for (int m = 1; m < 64; m <<= 1) {
    s += __shfl_xor(s, m);
    s2 += __shfl_xor(s2, m);
  }
  const float mu = s * (1.f / DIMM);
  const float rstd = rsqrtf(s2 * (1.f / DIMM) - mu * mu + EPS_);
#pragma unroll
  for (int c = 0; c < 3; ++c) {
    const float4 g4 = *reinterpret_cast<const float4*>(gamma + c * 256 + lane * 4);
    const float4 b4 = *reinterpret_cast<const float4*>(beta + c * 256 + lane * 4);
    bf16x4 o;
    o[0] = (bf16)((v[c].x - mu) * rstd * g4.x + b4.x);
    o[1] = (bf16)((v[c].y - mu) * rstd * g4.y + b4.y);
    o[2] = (bf16)((v[c].z - mu) * rstd * g4.z + b4.z);
    o[3] = (bf16)((v[c].w - mu) * rstd * g4.w + b4.w);
    *reinterpret_cast<bf16x4*>(xn + (size_t)row * DIMM + c * 256 + lane * 4) = o;
  }
}

// ------------- transpose + cast: f32 in[R][C] -> bf16 out[C][R] -------------
__global__ __launch_bounds__(256) void tcast_kernel(
    const float* __restrict__ in, bf16* __restrict__ out, int R, int C) {
  __shared__ float tile[32][33];
  const int tx = threadIdx.x & 31, ty = threadIdx.x >> 5;
  const int c0 = blockIdx.x * 32, r0 = blockIdx.y * 32;
#pragma unroll
  for (int i = ty; i < 32; i += 8)
    tile[i][tx] = in[(size_t)(r0 + i) * C + c0 + tx];
  __syncthreads();
#pragma unroll
  for (int i = ty; i < 32; i += 8)
    out[(size_t)(c0 + i) * R + r0 + tx] = (bf16)tile[tx][i];
}

// -------- QKV GEMM: xn(8192x768) @ wT(2304 cols x 768 k) -> q,k,vT bf16 --------
__global__ __launch_bounds__(256) void qkv_gemm(
    const bf16* __restrict__ xn, const bf16* __restrict__ wT,
    bf16* __restrict__ qb, bf16* __restrict__ kb, bf16* __restrict__ vt) {
  __shared__ __align__(16) bf16 As[128 * 32];
  __shared__ __align__(16) bf16 Bs[64 * 32];
  const int tid = threadIdx.x;
  const int wv = tid >> 6, l = tid & 63;
  const int l16 = l & 15, q4 = l >> 4;
  const int c0 = blockIdx.x * 64, row0 = blockIdx.y * 128;
  const int sr = tid >> 2, skk = (tid & 3) * 8;
  f32x4 acc0[4], acc1[4];
#pragma unroll
  for (int c = 0; c < 4; ++c) {
    acc0[c] = f32x4{0.f, 0.f, 0.f, 0.f};
    acc1[c] = f32x4{0.f, 0.f, 0.f, 0.f};
  }
  for (int k0 = 0; k0 < DIMM; k0 += 32) {
    __syncthreads();
    load_lds16(xn + (size_t)(row0 + sr) * DIMM + k0 + skk, As + tid * 8);
    load_lds16(xn + (size_t)(row0 + 64 + sr) * DIMM + k0 + skk, As + 2048 + tid * 8);
    load_lds16(wT + (size_t)(c0 + sr) * DIMM + k0 + skk, Bs + tid * 8);
    __syncthreads();
    const bf16x8 a0 = *reinterpret_cast<const bf16x8*>(&As[(wv * 32 + l16) * 32 + q4 * 8]);
    const bf16x8 a1 = *reinterpret_cast<const bf16x8*>(&As[(wv * 32 + 16 + l16) * 32 + q4 * 8]);
#pragma unroll
    for (int c = 0; c < 4; ++c) {
      const bf16x8 bb = *reinterpret_cast<const bf16x8*>(&Bs[(c * 16 + l16) * 32 + q4 * 8]);
      acc0[c] = MFMA16(a0, bb, acc0[c]);
      acc1[c] = MFMA16(a1, bb, acc1[c]);
    }
  }
  const int sect = c0 / DIMM;          // 0=q 1=k 2=v (uniform per block)
  const int head = (c0 % DIMM) >> 6;   // uniform per block
#pragma unroll
  for (int c = 0; c < 4; ++c) {
    const int dd = c * 16 + l16;
#pragma unroll
    for (int r = 0; r < 4; ++r) {
#pragma unroll
      for (int rsub = 0; rsub < 2; ++rsub) {
        const int gm = row0 + wv * 32 + rsub * 16 + q4 * 4 + r;
        const int b = gm >> 10, n = gm & 1023;
        const size_t bhh = (size_t)b * NHEADS + head;
        const float av = rsub ? acc1[c][r] : acc0[c][r];
        const bf16 val = (bf16)av;
        if (sect == 0)      qb[(bhh * NSEQ + n) * DH + dd] = val;
        else if (sect == 1) kb[(bhh * NSEQ + n) * DH + dd] = val;
        else                vt[(bhh * DH + dd) * NSEQ + n] = val;
      }
    }
  }
}

// -------- fused attention, chunked 3-phase with DMA-staged h --------
// Block: 16 q-rows; j in 2 chunks of 512 with flash-style online rescale.
// h is staged via global_load_lds DMA (zero VGPR in flight, 8KB/wave issued
// one chunk ahead) into wave-private h_lds rows; drained by a wave-local
// vmcnt(0) at P2 entry. P1: S=QK^T -> swizzled LDS. P2: blend from h_lds,
// contiguous blended stores, online softmax, P overwrites S. P3: PV with
// per-row rescale. LDS ~51KB -> 3 blocks/CU -> VGPR cap ~168 (no spill).
__global__ __launch_bounds__(256, 3) void attn_kernel(
    const bf16* __restrict__ qb, const bf16* __restrict__ kb,
    const bf16* __restrict__ vt, const float* __restrict__ h,
    float* __restrict__ blended, bf16* __restrict__ attn_out) {
  __shared__ __align__(16) char S_lds[16 * 1152];   // 18,432 B
  __shared__ __align__(16) float h_lds[16][512];    // 32,768 B
  __shared__ __align__(16) float scl[16];
  __shared__ __align__(16) float lred[16];

  const int tid = threadIdx.x;
  const int wv = tid >> 6, l = tid & 63;
  const int l16 = l & 15, q4 = l >> 4;
  const int i0 = blockIdx.x * 16;
  const int bh = blockIdx.y;

  const float* hbase = h + ((size_t)bh << 20);
  float* bbase = blended + ((size_t)bh << 20);
  const bf16* kbase = kb + (size_t)bh * NSEQ * DH;
  const bf16* vbase = vt + (size_t)bh * DH * NSEQ;

  // DMA: stage this wave's 4 rows (512 f32 each) of chunk c into h_lds.
  // 8 instructions x 1KB, zero VGPR cost, wave-private destination rows.
  auto DMAH = [&](int c) {
#pragma unroll
    for (int rr = 0; rr < 4; ++rr) {
      const int row = wv * 4 + rr;
#pragma unroll
      for (int hf = 0; hf < 2; ++hf)
        load_lds16(hbase + (size_t)(i0 + row) * NSEQ + c * 512 + hf * 256 + l * 4,
                   &h_lds[row][hf * 256]);
    }
  };

  bf16x8 qT[2];
#pragma unroll
  for (int w2 = 0; w2 < 2; ++w2)
    qT[w2] = *reinterpret_cast<const bf16x8*>(
        qb + ((size_t)bh * NSEQ + i0 + l16) * DH + w2 * 32 + q4 * 8);

  DMAH(0);  // chunk 0 h in flight across P1(0)

  f32x4 acc[4];
#pragma unroll
  for (int kk = 0; kk < 4; ++kk) acc[kk] = f32x4{0.f, 0.f, 0.f, 0.f};
  float m_run[4], l_run[4];
#pragma unroll
  for (int r = 0; r < 4; ++r) { m_run[r] = -1e30f; l_run[r] = 0.f; }

#pragma unroll
  for (int c = 0; c < 2; ++c) {
    // ---- P1: S chunk -> LDS (wave strip = 128 cols x all 16 rows) ----
    {
      const bf16* kq = kbase + (size_t)(c * 512 + wv * 128 + l16) * DH + q4 * 8;
      char* srow_w = S_lds + l16 * 1152;
#pragma unroll
      for (int st = 0; st < 2; ++st) {
        f32x4 s[4];
#pragma unroll
        for (int js = 0; js < 4; ++js) s[js] = f32x4{0.f, 0.f, 0.f, 0.f};
#pragma unroll
        for (int js = 0; js < 4; ++js) {
#pragma unroll
          for (int w2 = 0; w2 < 2; ++w2) {
            const bf16x8 kf = *reinterpret_cast<const bf16x8*>(
                kq + (size_t)(st * 64 + js * 16) * DH + w2 * 32);
            s[js] = MFMA16(kf, qT[w2], s[js]);
          }
        }
#pragma unroll
        for (int js = 0; js < 4; ++js) {
          bf16x4 pk;
#pragma unroll
          for (int r = 0; r < 4; ++r) pk[r] = (bf16)(s[js][r] * (ALPHA_ * SCALE_));
          const int cb = (wv * 256 + st * 128 + js * 32 + q4 * 8);
          *reinterpret_cast<bf16x4*>(srow_w + swz(l16, cb)) = pk;
        }
      }
    }
    BAR_LGKM();  // S visible
    WAIT_VM0();  // this wave's h DMAs for chunk c landed

    // ---- P2: stream 4 full rows from h_lds; online softmax; P->LDS ----
#pragma unroll
    for (int rr = 0; rr < 4; ++rr) {
      const int row = wv * 4 + rr;
      char* srow = S_lds + row * 1152;
      const bf16x8 sv = *reinterpret_cast<const bf16x8*>(srow + swz(row, l * 16));
      const f32x4 h0 = *reinterpret_cast<const f32x4*>(&h_lds[row][l * 8]);
      const f32x4 h1 = *reinterpret_cast<const f32x4*>(&h_lds[row][l * 8 + 4]);
      float bl[8];
#pragma unroll
      for (int t = 0; t < 4; ++t) bl[t] = fmaf(0.75f, h0[t], (float)sv[t]);
#pragma unroll
      for (int t = 0; t < 4; ++t) bl[4 + t] = fmaf(0.75f, h1[t], (float)sv[4 + t]);
      float* bp = bbase + (size_t)(i0 + row) * NSEQ + c * 512 + l * 8;
      f32x4 b0, b1;
#pragma unroll
      for (int t = 0; t < 4; ++t) { b0[t] = bl[t]; b1[t] = bl[4 + t]; }
      *reinterpret_cast<f32x4*>(bp) = b0;
      *reinterpret_cast<f32x4*>(bp + 4) = b1;
      float tm = bl[0];
#pragma unroll
      for (int t = 1; t < 8; ++t) tm = fmaxf(tm, bl[t]);
#pragma unroll
      for (int mm = 1; mm < 64; mm <<= 1) tm = fmaxf(tm, __shfl_xor(tm, mm));
      const float mnew = fmaxf(m_run[rr], tm);
      const float sc = __expf(m_run[rr] - mnew);
      m_run[rr] = mnew;
      float rs = 0.f;
      bf16x8 pk;
#pragma unroll
      for (int t = 0; t < 8; ++t) {
        const float p = __expf(bl[t] - mnew);
        rs += p;
        pk[t] = (bf16)p;
      }
      *reinterpret_cast<bf16x8*>(srow + swz(row, l * 16)) = pk;
#pragma unroll
      for (int mm = 1; mm < 64; mm <<= 1) rs += __shfl_xor(rs, mm);
      l_run[rr] = l_run[rr] * sc + rs;
      if (l == 0) {
        scl[row] = sc;
        if (c == 1) lred[row] = l_run[rr];
      }
    }
    // issue next chunk's h DMA now: in flight across P3(c) + P1(c+1)
    if (c == 0) DMAH(1);
    BAR_LGKM();  // P, scl (and final lred) visible

    // ---- P3: acc = acc*scl + P @ V^T (wave owns d-strip wv*16..+15) ----
    {
      const f32x4 sclv = *reinterpret_cast<const f32x4*>(&scl[q4 * 4]);
      const bf16* vq = vbase + (size_t)(wv * 16 + l16) * NSEQ + c * 512 + q4 * 8;
      char* prow = S_lds + l16 * 1152;
#pragma unroll
      for (int kk = 0; kk < 4; ++kk) acc[kk] *= sclv;
#pragma unroll
      for (int kk = 0; kk < 4; ++kk) {
#pragma unroll
        for (int ki = 0; ki < 4; ++ki) {
          const int ks = kk * 4 + ki;
          const bf16x8 pa = *reinterpret_cast<const bf16x8*>(
              prow + swz(l16, ks * 64 + q4 * 16));
          const bf16x8 vf = *reinterpret_cast<const bf16x8*>(vq + ks * 32);
          acc[kk] = MFMA16(pa, vf, acc[kk]);
        }
      }
    }
    if (c == 0) BAR_LGKM();  // S_lds free for next chunk's P1
  }

  // ---- epilogue: normalize, write attn_out ----
  const f32x4 lv = *reinterpret_cast<const f32x4*>(&lred[q4 * 4]);
  const f32x4 af = (acc[0] + acc[1]) + (acc[2] + acc[3]);
  const int b = bh / NHEADS, head = bh % NHEADS;
#pragma unroll
  for (int r = 0; r < 4; ++r) {
    const int q = q4 * 4 + r;
    attn_out[((size_t)b * NSEQ + i0 + q) * DIMM + head * DH + wv * 16 + l16] =
        (bf16)(af[r] / lv[r]);
  }
}

// -------- output projection: attn_out(8192x768) @ woutT + b_out -> f32 out --------
__global__ __launch_bounds__(256) void oproj_gemm(
    const bf16* __restrict__ ain, const bf16* __restrict__ wT,
    const float* __restrict__ bias, float* __restrict__ out) {
  __shared__ __align__(16) bf16 As[128 * 32];
  __shared__ __align__(16) bf16 Bs[64 * 32];
  const int tid = threadIdx.x;
  const int wv = tid >> 6, l = tid & 63;
  const int l16 = l & 15, q4 = l >> 4;
  const int c0 = blockIdx.x * 64, row0 = blockIdx.y * 128;
  const int sr = tid >> 2, skk = (tid & 3) * 8;
  f32x4 acc0[4], acc1[4];
#pragma unroll
  for (int c = 0; c < 4; ++c) {
    acc0[c] = f32x4{0.f, 0.f, 0.f, 0.f};
    acc1[c] = f32x4{0.f, 0.f, 0.f, 0.f};
  }
  for (int k0 = 0; k0 < DIMM; k0 += 32) {
    __syncthreads();
    load_lds16(ain + (size_t)(row0 + sr) * DIMM + k0 + skk, As + tid * 8);
    load_lds16(ain + (size_t)(row0 + 64 + sr) * DIMM + k0 + skk, As + 2048 + tid * 8);
    load_lds16(wT + (size_t)(c0 + sr) * DIMM + k0 + skk, Bs + tid * 8);
    __syncthreads();
    const bf16x8 a0 = *reinterpret_cast<const bf16x8*>(&As[(wv * 32 + l16) * 32 + q4 * 8]);
    const bf16x8 a1 = *reinterpret_cast<const bf16x8*>(&As[(wv * 32 + 16 + l16) * 32 + q4 * 8]);
#pragma unroll
    for (int c = 0; c < 4; ++c) {
      const bf16x8 bb = *reinterpret_cast<const bf16x8*>(&Bs[(c * 16 + l16) * 32 + q4 * 8]);
      acc0[c] = MFMA16(a0, bb, acc0[c]);
      acc1[c] = MFMA16(a1, bb, acc1[c]);
    }
  }
#pragma unroll
  for (int c = 0; c < 4; ++c) {
    const int gc = c0 + c * 16 + l16;
    const float bv = bias[gc];
#pragma unroll
    for (int r = 0; r < 4; ++r) {
      out[(size_t)(row0 + wv * 32 + q4 * 4 + r) * DIMM + gc] = acc0[c][r] + bv;
      out[(size_t)(row0 + wv * 32 + 16 + q4 * 4 + r) * DIMM + gc] = acc1[c][r] + bv;
    }
  }
}

extern "C" void kernel_launch(void* const* d_in, const int* in_sizes, int n_in,
                              void* d_out, int out_size, void* d_ws, size_t ws_size,
                              hipStream_t stream) {
  const float* x = (const float*)d_in[0];
  const float* h = (const float*)d_in[1];
  const float* gamma = (const float*)d_in[2];
  const float* beta = (const float*)d_in[3];
  const float* w_qkv = (const float*)d_in[4];
  const float* w_out = (const float*)d_in[5];
  const float* b_out = (const float*)d_in[6];
  float* out = (float*)d_out;
  float* blended = out + (size_t)NB * NSEQ * DIMM;

  char* ws = (char*)d_ws;
  bf16* xn = (bf16*)(ws);                   // 12.6 MB; reused as attn_out after qkv_gemm
  bf16* qb = (bf16*)(ws + 12582912);
  bf16* kb = (bf16*)(ws + 25165824);
  bf16* vt = (bf16*)(ws + 37748736);
  bf16* wqkvT = (bf16*)(ws + 50331648);
  bf16* woutT = (bf16*)(ws + 53870592);

  hipLaunchKernelGGL(ln_kernel, dim3(2048), dim3(256), 0, stream, x, gamma, beta, xn);
  hipLaunchKernelGGL(tcast_kernel, dim3(72, 24), dim3(256), 0, stream, w_qkv, wqkvT, DIMM, NQKV);
  hipLaunchKernelGGL(tcast_kernel, dim3(24, 24), dim3(256), 0, stream, w_out, woutT, DIMM, DIMM);
  hipLaunchKernelGGL(qkv_gemm, dim3(36, 64), dim3(256), 0, stream, xn, wqkvT, qb, kb, vt);
  hipLaunchKernelGGL(attn_kernel, dim3(64, 96), dim3(256), 0, stream, qb, kb, vt, h, blended, xn);
  hipLaunchKernelGGL(oproj_gemm, dim3(12, 64), dim3(256), 0, stream, xn, woutT, b_out, out);
}